// Round 1
// baseline (724.288 us; speedup 1.0000x reference)
//
#include <hip/hip_runtime.h>

// LSTM: B=2048, T=512, F=60, H=7, 2 layers, PyTorch gate order (i,f,g,o).
// Layout: 32 lanes per batch element (28 active = one per gate row),
// 2 batch groups per wave64, block=256 (8 batches), grid=256 -> 1024 waves.
// Layer pipelining: body(t) computes layer0(t) || layer1(t-1) (independent).

#define B_ 2048
#define T_ 512
#define F_ 60
#define H_ 7
#define G4 28  // 4*H

__device__ __forceinline__ float rcpf_(float v) { return __builtin_amdgcn_rcpf(v); }

// dot of 7-element weight row with h vector, tree-shaped, seeded with `seed`
__device__ __forceinline__ float dot7(const float* w, const float* h, float seed) {
    float m01 = fmaf(w[1], h[1], w[0] * h[0]);
    float m23 = fmaf(w[3], h[3], w[2] * h[2]);
    float m45 = fmaf(w[5], h[5], w[4] * h[4]);
    float m6  = fmaf(w[6], h[6], seed);
    return (m01 + m23) + (m45 + m6);
}

__global__ __launch_bounds__(256, 1)
void lstm2_kernel(const float* __restrict__ x,
                  const float* __restrict__ Wih0, const float* __restrict__ Whh0,
                  const float* __restrict__ bih0, const float* __restrict__ bhh0,
                  const float* __restrict__ Wih1, const float* __restrict__ Whh1,
                  const float* __restrict__ bih1, const float* __restrict__ bhh1,
                  float* __restrict__ out)
{
    const int tid   = threadIdx.x;
    const int lane  = tid & 63;
    const int wbase = lane & 32;        // 0 or 32: which half-wave group
    const int g     = lane & 31;        // gate-row slot within group (0..31)
    const int u     = g;                // unit index for combine lanes (valid u<7)
    const int r     = (g < G4) ? g : (G4 - 1);  // clamp idle lanes 28..31
    const int b     = blockIdx.x * 8 + (tid >> 5);

    // ---- per-lane weights in registers ----
    float wi[F_];
    #pragma unroll
    for (int k = 0; k < F_; ++k) wi[k] = Wih0[r * F_ + k];
    float wh0[H_], wi1[H_], wh1[H_];
    #pragma unroll
    for (int v = 0; v < H_; ++v) {
        wh0[v] = Whh0[r * H_ + v];
        wi1[v] = Wih1[r * H_ + v];
        wh1[v] = Whh1[r * H_ + v];
    }
    const float bias0 = bih0[r] + bhh0[r];
    const float bias1 = bih1[r] + bhh1[r];

    // rows 14..20 are the cell gate 'g' -> tanh; others sigmoid.
    // act(a) = A * rcp(1 + exp(-K*a)) + C   (sigmoid: 1,1,0; tanh: 2,2,-1)
    const bool isT = (r >= 2 * H_ && r < 3 * H_);
    const float Ka = isT ? 2.f : 1.f;
    const float Aa = isT ? 2.f : 1.f;
    const float Ca = isT ? -1.f : 0.f;

    float h0v[H_] = {0, 0, 0, 0, 0, 0, 0};
    float h1v[H_] = {0, 0, 0, 0, 0, 0, 0};
    float c0 = 0.f, c1 = 0.f;
    float h1new = 0.f;

    const float4* xrow0 = (const float4*)(x + (size_t)b * T_ * F_);

    // ---- prologue: a_in(0) = bias0 + Wih0[r,:] . x[b,0,:] ----
    float a_in;
    {
        float4 q[15];
        #pragma unroll
        for (int j = 0; j < 15; ++j) q[j] = xrow0[j];
        float s0 = 0.f, s1 = 0.f, s2 = 0.f, s3 = 0.f;
        #pragma unroll
        for (int j = 0; j < 15; ++j) {
            s0 = fmaf(wi[4 * j + 0], q[j].x, s0);
            s1 = fmaf(wi[4 * j + 1], q[j].y, s1);
            s2 = fmaf(wi[4 * j + 2], q[j].z, s2);
            s3 = fmaf(wi[4 * j + 3], q[j].w, s3);
        }
        a_in = bias0 + ((s0 + s1) + (s2 + s3));
    }

    for (int t = 0; t < T_; ++t) {
        // prefetch x(t+1) (clamped reload at the end; independent of state)
        const int tn = (t + 1 < T_) ? (t + 1) : t;
        const float4* xr = xrow0 + tn * 15;
        float4 q[15];
        #pragma unroll
        for (int j = 0; j < 15; ++j) q[j] = xr[j];

        // ---- layer0 step t (uses h0v = h0(t-1)) ----
        float a0   = dot7(wh0, h0v, a_in);
        float act0 = fmaf(Aa, rcpf_(1.f + __expf(-Ka * a0)), Ca);
        float f0 = __shfl(act0, wbase + u + 7, 64);
        float g0 = __shfl(act0, wbase + u + 14, 64);
        float o0 = __shfl(act0, wbase + u + 21, 64);

        // ---- layer1 step t-1 (uses h0v = h0(t-1), h1v = h1(t-2)) ----
        float a1   = dot7(wi1, h0v, bias1);
        a1         = dot7(wh1, h1v, a1);
        float act1 = fmaf(Aa, rcpf_(1.f + __expf(-Ka * a1)), Ca);
        float f1 = __shfl(act1, wbase + u + 7, 64);
        float g1 = __shfl(act1, wbase + u + 14, 64);
        float o1 = __shfl(act1, wbase + u + 21, 64);

        // ---- commit layer0: c0/h0 (lanes u<7 hold real state) ----
        c0 = fmaf(f0, c0, act0 * g0);
        float th0   = fmaf(2.f, rcpf_(1.f + __expf(-2.f * c0)), -1.f);
        float h0new = o0 * th0;

        // ---- commit layer1 (skip the t==0 phantom step) ----
        if (t > 0) {
            c1 = fmaf(f1, c1, act1 * g1);
            float th1 = fmaf(2.f, rcpf_(1.f + __expf(-2.f * c1)), -1.f);
            h1new = o1 * th1;
            #pragma unroll
            for (int v = 0; v < H_; ++v) h1v[v] = __shfl(h1new, wbase + v, 64);
        }

        // broadcast h0(t) to all lanes of the group
        #pragma unroll
        for (int v = 0; v < H_; ++v) h0v[v] = __shfl(h0new, wbase + v, 64);

        // ---- a_in(t+1) = bias0 + Wih0[r,:] . x[b,t+1,:] ----
        float s0 = 0.f, s1 = 0.f, s2 = 0.f, s3 = 0.f;
        #pragma unroll
        for (int j = 0; j < 15; ++j) {
            s0 = fmaf(wi[4 * j + 0], q[j].x, s0);
            s1 = fmaf(wi[4 * j + 1], q[j].y, s1);
            s2 = fmaf(wi[4 * j + 2], q[j].z, s2);
            s3 = fmaf(wi[4 * j + 3], q[j].w, s3);
        }
        a_in = bias0 + ((s0 + s1) + (s2 + s3));
    }

    // ---- epilogue: layer1 step T-1 (uses h0v = h0(T-1), h1v = h1(T-2)) ----
    {
        float a1   = dot7(wi1, h0v, bias1);
        a1         = dot7(wh1, h1v, a1);
        float act1 = fmaf(Aa, rcpf_(1.f + __expf(-Ka * a1)), Ca);
        float f1 = __shfl(act1, wbase + u + 7, 64);
        float g1 = __shfl(act1, wbase + u + 14, 64);
        float o1 = __shfl(act1, wbase + u + 21, 64);
        c1 = fmaf(f1, c1, act1 * g1);
        float th1 = fmaf(2.f, rcpf_(1.f + __expf(-2.f * c1)), -1.f);
        h1new = o1 * th1;
    }

    if (u < H_) {
        out[(size_t)b * H_ + u] = h1new;
    }
}

extern "C" void kernel_launch(void* const* d_in, const int* in_sizes, int n_in,
                              void* d_out, int out_size, void* d_ws, size_t ws_size,
                              hipStream_t stream) {
    const float* x    = (const float*)d_in[0];
    const float* Wih0 = (const float*)d_in[1];
    const float* Whh0 = (const float*)d_in[2];
    const float* bih0 = (const float*)d_in[3];
    const float* bhh0 = (const float*)d_in[4];
    const float* Wih1 = (const float*)d_in[5];
    const float* Whh1 = (const float*)d_in[6];
    const float* bih1 = (const float*)d_in[7];
    const float* bhh1 = (const float*)d_in[8];
    float* out = (float*)d_out;

    dim3 grid(B_ / 8);
    dim3 block(256);
    lstm2_kernel<<<grid, block, 0, stream>>>(x, Wih0, Whh0, bih0, bhh0,
                                             Wih1, Whh1, bih1, bhh1, out);
}

// Round 2
// 659.307 us; speedup vs baseline: 1.0986x; 1.0986x over previous
//
#include <hip/hip_runtime.h>

// 2-layer LSTM: B=2048, T=512, F=60, H=7, PyTorch gate order (i,f,g,o).
// Layout: 32 lanes per batch element (28 active = one per gate row),
// 2 batch groups per wave64, block=256 (8 batches), grid=256 -> 1024 waves.
// Layer pipelining: body(t) computes layer0(t) || layer1(t-1) (independent).
// x staged through double-buffered LDS in 16-step chunks: global loads for
// chunk k+1 issued at top of chunk k (latency hidden by ~5000 cyc of compute),
// ds_write + one barrier per chunk. Per-step x reads are ds_read_b128
// broadcasts (free 2-way per wave).

#define B_ 2048
#define T_ 512
#define F_ 60
#define H_ 7
#define G4 28   // 4*H
#define CH 16   // timesteps per LDS chunk
#define NCH (T_ / CH)           // 32 chunks
#define F4 (F_ / 4)             // 15 float4 per row
#define ROW4 (CH * F4)          // 240 float4 per batch per chunk
#define TOT4 (8 * ROW4)         // 1920 float4 per block chunk

__device__ __forceinline__ float rcpf_(float v) { return __builtin_amdgcn_rcpf(v); }

__device__ __forceinline__ float dot7(const float* w, const float* h, float seed) {
    float m01 = fmaf(w[1], h[1], w[0] * h[0]);
    float m23 = fmaf(w[3], h[3], w[2] * h[2]);
    float m45 = fmaf(w[5], h[5], w[4] * h[4]);
    float m6  = fmaf(w[6], h[6], seed);
    return (m01 + m23) + (m45 + m6);
}

// 60-MAC input projection from an LDS row (15 float4), pairwise to invite
// v_pk_fma_f32 packing.
__device__ __forceinline__ float proj60(const float* wi, const float4* row, float bias) {
    float s0 = 0.f, s1 = 0.f, s2 = 0.f, s3 = 0.f;
    #pragma unroll
    for (int j = 0; j < F4; ++j) {
        float4 q = row[j];
        s0 = fmaf(wi[4 * j + 0], q.x, s0);
        s1 = fmaf(wi[4 * j + 1], q.y, s1);
        s2 = fmaf(wi[4 * j + 2], q.z, s2);
        s3 = fmaf(wi[4 * j + 3], q.w, s3);
    }
    return bias + ((s0 + s1) + (s2 + s3));
}

__global__ __launch_bounds__(256, 1)
void lstm2_kernel(const float* __restrict__ x,
                  const float* __restrict__ Wih0, const float* __restrict__ Whh0,
                  const float* __restrict__ bih0, const float* __restrict__ bhh0,
                  const float* __restrict__ Wih1, const float* __restrict__ Whh1,
                  const float* __restrict__ bih1, const float* __restrict__ bhh1,
                  float* __restrict__ out)
{
    __shared__ float4 lds4[2][8][ROW4];   // 61440 B

    const int tid   = threadIdx.x;
    const int lane  = tid & 63;
    const int wbase = lane & 32;
    const int g     = lane & 31;
    const int u     = g;
    const int r     = (g < G4) ? g : (G4 - 1);
    const int grp   = tid >> 5;                 // batch slot within block, 0..7
    const int b     = blockIdx.x * 8 + grp;

    // ---- per-lane weights in registers ----
    float wi[F_];
    #pragma unroll
    for (int k = 0; k < F_; ++k) wi[k] = Wih0[r * F_ + k];
    float wh0[H_], wi1[H_], wh1[H_];
    #pragma unroll
    for (int v = 0; v < H_; ++v) {
        wh0[v] = Whh0[r * H_ + v];
        wi1[v] = Wih1[r * H_ + v];
        wh1[v] = Whh1[r * H_ + v];
    }
    const float bias0 = bih0[r] + bhh0[r];
    const float bias1 = bih1[r] + bhh1[r];

    const bool isT = (r >= 2 * H_ && r < 3 * H_);
    const float Ka = isT ? 2.f : 1.f;
    const float Aa = isT ? 2.f : 1.f;
    const float Ca = isT ? -1.f : 0.f;

    float h0v[H_] = {0, 0, 0, 0, 0, 0, 0};
    float h1v[H_] = {0, 0, 0, 0, 0, 0, 0};
    float c0 = 0.f, c1 = 0.f;
    float h1new = 0.f;

    // block's x base, as float4; batch bl's row-chunk is contiguous
    const float4* __restrict__ xb =
        (const float4*)(x + (size_t)(blockIdx.x * 8) * T_ * F_);
    // per-batch float4 stride over full sequence:
    const int XB4 = T_ * F4;   // 7680

    // ---- stage chunk 0 ----
    #pragma unroll
    for (int i0 = 0; i0 < 8; ++i0) {
        int idx = tid + 256 * i0;
        if (idx < TOT4) {
            int bl = idx / ROW4;
            int j  = idx - bl * ROW4;
            lds4[0][bl][j] = xb[bl * XB4 + j];
        }
    }
    __syncthreads();

    float a_in = proj60(wi, &lds4[0][grp][0], bias0);

    for (int ch = 0; ch < NCH; ++ch) {
        // issue global prefetch for next chunk (clamped reload on last)
        const int cn = (ch < NCH - 1) ? ch + 1 : ch;
        float4 st[8];
        #pragma unroll
        for (int i0 = 0; i0 < 8; ++i0) {
            int idx = tid + 256 * i0;
            if (idx < TOT4) {
                int bl = idx / ROW4;
                int j  = idx - bl * ROW4;
                st[i0] = xb[bl * XB4 + cn * ROW4 + j];
            }
        }

        const int buf = ch & 1;
        const float4* __restrict__ rowbase = &lds4[buf][grp][0];

        #pragma unroll
        for (int s = 0; s < CH; ++s) {
            const int t = ch * CH + s;

            // ---- layer0 step t (uses h0v = h0(t-1)) ----
            float a0   = dot7(wh0, h0v, a_in);
            float act0 = fmaf(Aa, rcpf_(1.f + __expf(-Ka * a0)), Ca);
            float f0 = __shfl(act0, wbase + u + 7, 64);
            float g0 = __shfl(act0, wbase + u + 14, 64);
            float o0 = __shfl(act0, wbase + u + 21, 64);

            // ---- layer1 step t-1 (uses h0v = h0(t-1), h1v = h1(t-2)) ----
            float a1   = dot7(wi1, h0v, bias1);
            a1         = dot7(wh1, h1v, a1);
            float act1 = fmaf(Aa, rcpf_(1.f + __expf(-Ka * a1)), Ca);
            float f1 = __shfl(act1, wbase + u + 7, 64);
            float g1 = __shfl(act1, wbase + u + 14, 64);
            float o1 = __shfl(act1, wbase + u + 21, 64);

            // ---- commit layer0 ----
            c0 = fmaf(f0, c0, act0 * g0);
            float th0   = fmaf(2.f, rcpf_(1.f + __expf(-2.f * c0)), -1.f);
            float h0new = o0 * th0;

            // ---- commit layer1 (skip t==0 phantom) ----
            if (t > 0) {
                c1 = fmaf(f1, c1, act1 * g1);
                float th1 = fmaf(2.f, rcpf_(1.f + __expf(-2.f * c1)), -1.f);
                h1new = o1 * th1;
                #pragma unroll
                for (int v = 0; v < H_; ++v) h1v[v] = __shfl(h1new, wbase + v, 64);
            }

            // broadcast h0(t)
            #pragma unroll
            for (int v = 0; v < H_; ++v) h0v[v] = __shfl(h0new, wbase + v, 64);

            // a_in(t+1) from LDS (same chunk); chunk-boundary handled below
            if (s < CH - 1) a_in = proj60(wi, rowbase + (s + 1) * F4, bias0);
        }

        // commit staged chunk to the other buffer
        #pragma unroll
        for (int i0 = 0; i0 < 8; ++i0) {
            int idx = tid + 256 * i0;
            if (idx < TOT4) {
                int bl = idx / ROW4;
                int j  = idx - bl * ROW4;
                lds4[buf ^ 1][bl][j] = st[i0];
            }
        }
        __syncthreads();

        if (ch < NCH - 1) a_in = proj60(wi, &lds4[buf ^ 1][grp][0], bias0);
    }

    // ---- epilogue: layer1 step T-1 ----
    {
        float a1   = dot7(wi1, h0v, bias1);
        a1         = dot7(wh1, h1v, a1);
        float act1 = fmaf(Aa, rcpf_(1.f + __expf(-Ka * a1)), Ca);
        float f1 = __shfl(act1, wbase + u + 7, 64);
        float g1 = __shfl(act1, wbase + u + 14, 64);
        float o1 = __shfl(act1, wbase + u + 21, 64);
        c1 = fmaf(f1, c1, act1 * g1);
        float th1 = fmaf(2.f, rcpf_(1.f + __expf(-2.f * c1)), -1.f);
        h1new = o1 * th1;
    }

    if (u < H_) {
        out[(size_t)b * H_ + u] = h1new;
    }
}

extern "C" void kernel_launch(void* const* d_in, const int* in_sizes, int n_in,
                              void* d_out, int out_size, void* d_ws, size_t ws_size,
                              hipStream_t stream) {
    const float* x    = (const float*)d_in[0];
    const float* Wih0 = (const float*)d_in[1];
    const float* Whh0 = (const float*)d_in[2];
    const float* bih0 = (const float*)d_in[3];
    const float* bhh0 = (const float*)d_in[4];
    const float* Wih1 = (const float*)d_in[5];
    const float* Whh1 = (const float*)d_in[6];
    const float* bih1 = (const float*)d_in[7];
    const float* bhh1 = (const float*)d_in[8];
    float* out = (float*)d_out;

    dim3 grid(B_ / 8);
    dim3 block(256);
    lstm2_kernel<<<grid, block, 0, stream>>>(x, Wih0, Whh0, bih0, bhh0,
                                             Wih1, Whh1, bih1, bhh1, out);
}

// Round 3
// 569.772 us; speedup vs baseline: 1.2712x; 1.1571x over previous
//
#include <hip/hip_runtime.h>

// 2-layer LSTM: B=2048, T=512, F=60, H=7, PyTorch gate order (i,f,g,o).
//
// Mapping: ONE WAVE PER BATCH (2048 waves -> 2 waves/SIMD).
//   lanes  0..27 : layer0 gate rows (i,f,g,o x 7 units), step t
//   lanes 32..59 : layer1 gate rows, step t-1 (layer pipeline on lanes)
// Unified per-step stream: a = seed + dot7(wA,h0v) + dot7(wB,h1v)
//   L0: wA=Whh0[r], wB=0,       seed=a_in(t) (input projection + bias0)
//   L1: wA=Wih1[r], wB=Whh1[r], seed=bias1
// Input projection split across partner lanes (L0 lane: x[0:32), L1 lane:
// x[28:60) with first 4 weights zeroed), combined via one xor-32 shuffle.
// h broadcasts via v_readlane -> SGPRs (no DS pipe, short latency).
// x staged through double-buffered LDS in 16-step chunks; 4 float4/thread
// staging registers (no spill).

#define B_ 2048
#define T_ 512
#define F_ 60
#define H_ 7
#define G4 28
#define CH 16
#define NCH (T_ / CH)     // 32
#define F4 15             // float4 per x row
#define ROW4 (CH * F4)    // 240 float4 per batch per chunk
#define BPB 4             // batches (waves) per block
#define TOT4 (BPB * ROW4) // 960
#define L2E 1.4426950408889634f

#if __has_builtin(__builtin_amdgcn_exp2f)
#define EXP2(x) __builtin_amdgcn_exp2f(x)
#else
#define EXP2(x) exp2f(x)
#endif

__device__ __forceinline__ float rcpf_(float v) { return __builtin_amdgcn_rcpf(v); }

__device__ __forceinline__ float bcast(float v, int srclane) {
    return __uint_as_float(__builtin_amdgcn_readlane(__float_as_uint(v), srclane));
}

// seeded 7-MAC dot, tree shaped. h[] values are wave-uniform (SGPRs).
__device__ __forceinline__ float dot7(const float* w, const float* h, float seed) {
    float m01 = fmaf(w[1], h[1], w[0] * h[0]);
    float m23 = fmaf(w[3], h[3], w[2] * h[2]);
    float m45 = fmaf(w[5], h[5], w[4] * h[4]);
    float m6  = fmaf(w[6], h[6], seed);
    return (m01 + m23) + (m45 + m6);
}

// 32-MAC half-projection from LDS row (8 float4 broadcasts)
__device__ __forceinline__ float proj32(const float* pw, const float4* rp, float seed) {
    float s0 = seed, s1 = 0.f, s2 = 0.f, s3 = 0.f;
    #pragma unroll
    for (int j = 0; j < 8; ++j) {
        float4 q = rp[j];
        s0 = fmaf(pw[4 * j + 0], q.x, s0);
        s1 = fmaf(pw[4 * j + 1], q.y, s1);
        s2 = fmaf(pw[4 * j + 2], q.z, s2);
        s3 = fmaf(pw[4 * j + 3], q.w, s3);
    }
    return (s0 + s1) + (s2 + s3);
}

__global__ __launch_bounds__(256, 2)
void lstm2_kernel(const float* __restrict__ x,
                  const float* __restrict__ Wih0, const float* __restrict__ Whh0,
                  const float* __restrict__ bih0, const float* __restrict__ bhh0,
                  const float* __restrict__ Wih1, const float* __restrict__ Whh1,
                  const float* __restrict__ bih1, const float* __restrict__ bhh1,
                  float* __restrict__ out)
{
    __shared__ float4 lds4[2][BPB][ROW4];   // 30720 B

    const int tid   = threadIdx.x;
    const int lane  = tid & 63;
    const bool isL1 = lane >= 32;
    const int g     = lane & 31;
    const int u     = g;
    const int r     = (g < G4) ? g : (G4 - 1);
    const int grp   = tid >> 6;                 // wave slot = batch slot, 0..3
    const int b     = blockIdx.x * BPB + grp;

    // ---- per-lane weights ----
    float pw[32];   // half of Wih0 row r
    {
        const int offs = isL1 ? 28 : 0;
        #pragma unroll
        for (int k = 0; k < 32; ++k) pw[k] = Wih0[r * F_ + offs + k];
        if (isL1) { pw[0] = pw[1] = pw[2] = pw[3] = 0.f; }  // overlap zeroed
    }
    float wA[H_], wB[H_];
    #pragma unroll
    for (int v = 0; v < H_; ++v) {
        wA[v] = isL1 ? Wih1[r * H_ + v] : Whh0[r * H_ + v];
        wB[v] = isL1 ? Whh1[r * H_ + v] : 0.f;
    }
    const float bias0 = bih0[r] + bhh0[r];   // used on L0 lanes (proj seed)
    const float bias1 = bih1[r] + bhh1[r];   // used on L1 lanes (step seed)

    const bool isT = (r >= 2 * H_ && r < 3 * H_);   // cell gate -> tanh
    const float KK = isT ? (-2.f * L2E) : (-L2E);
    const float Aa = isT ? 2.f : 1.f;
    const float Ca = isT ? -1.f : 0.f;

    float h0v[H_] = {0, 0, 0, 0, 0, 0, 0};   // wave-uniform (SGPRs)
    float h1v[H_] = {0, 0, 0, 0, 0, 0, 0};
    float c = 0.f;        // c0 on L0 lanes, c1 on L1 lanes
    float hnew = 0.f;

    const float4* __restrict__ xb =
        (const float4*)(x + (size_t)(blockIdx.x * BPB) * T_ * F_);
    const int XB4 = T_ * F4;             // 7680 float4 per batch
    const int lofs = isL1 ? 7 : 0;       // LDS read offset (floats 28..59)
    const float pseed = isL1 ? 0.f : bias0;

    // ---- stage chunk 0 ----
    #pragma unroll
    for (int i = 0; i < 4; ++i) {
        int idx = tid + 256 * i;
        if (idx < TOT4) {
            int bl = idx / ROW4;
            int j  = idx - bl * ROW4;
            lds4[0][bl][j] = xb[bl * XB4 + j];
        }
    }
    __syncthreads();

    float a_in;
    {
        float ow = proj32(pw, &lds4[0][grp][0] + lofs, pseed);
        a_in = ow + __shfl(ow, lane ^ 32, 64);
    }

    for (int ch = 0; ch < NCH; ++ch) {
        // prefetch next chunk into 4 regs (clamped reload on last chunk)
        const int cn = (ch < NCH - 1) ? ch + 1 : ch;
        float4 st[4];
        #pragma unroll
        for (int i = 0; i < 4; ++i) {
            int idx = tid + 256 * i;
            if (idx < TOT4) {
                int bl = idx / ROW4;
                int j  = idx - bl * ROW4;
                st[i] = xb[bl * XB4 + cn * ROW4 + j];
            }
        }

        const int buf = ch & 1;
        const float4* __restrict__ rowb = &lds4[buf][grp][0] + lofs;

        #pragma unroll
        for (int s = 0; s < CH; ++s) {
            // ---- unified gate preactivation ----
            float seed = isL1 ? bias1 : a_in;
            float a = dot7(wA, h0v, seed);
            a = dot7(wB, h1v, a);
            float act = fmaf(Aa, rcpf_(1.f + EXP2(KK * a)), Ca);

            // gather f,g,o partners (within own half-wave for real lanes)
            float fg = __shfl(act, lane + 7, 64);
            float gg = __shfl(act, lane + 14, 64);
            float og = __shfl(act, lane + 21, 64);

            // ---- cell update (c0 on L0, c1 on L1) ----
            float cnew = fmaf(fg, c, act * gg);
            if (ch == 0 && s == 0) cnew = isL1 ? 0.f : cnew;  // phantom L1 step
            c = cnew;
            float th = fmaf(2.f, rcpf_(1.f + EXP2(-2.f * L2E * c)), -1.f);
            hnew = og * th;

            // ---- broadcasts via readlane (SGPRs) ----
            #pragma unroll
            for (int v = 0; v < H_; ++v) h0v[v] = bcast(hnew, v);
            if (ch > 0 || s > 0) {
                #pragma unroll
                for (int v = 0; v < H_; ++v) h1v[v] = bcast(hnew, 32 + v);
            }

            // ---- a_in(t+1) from LDS (chunk-boundary handled below) ----
            if (s < CH - 1) {
                float ow = proj32(pw, rowb + (s + 1) * F4, pseed);
                a_in = ow + __shfl(ow, lane ^ 32, 64);
            }
        }

        // commit staged chunk to the other buffer
        #pragma unroll
        for (int i = 0; i < 4; ++i) {
            int idx = tid + 256 * i;
            if (idx < TOT4) {
                int bl = idx / ROW4;
                int j  = idx - bl * ROW4;
                lds4[buf ^ 1][bl][j] = st[i];
            }
        }
        __syncthreads();

        if (ch < NCH - 1) {
            float ow = proj32(pw, &lds4[buf ^ 1][grp][0] + lofs, pseed);
            a_in = ow + __shfl(ow, lane ^ 32, 64);
        }
    }

    // ---- epilogue: layer1 step T-1 (real on L1 lanes) ----
    {
        float seed = isL1 ? bias1 : 0.f;
        float a = dot7(wA, h0v, seed);
        a = dot7(wB, h1v, a);
        float act = fmaf(Aa, rcpf_(1.f + EXP2(KK * a)), Ca);
        float fg = __shfl(act, lane + 7, 64);
        float gg = __shfl(act, lane + 14, 64);
        float og = __shfl(act, lane + 21, 64);
        c = fmaf(fg, c, act * gg);
        float th = fmaf(2.f, rcpf_(1.f + EXP2(-2.f * L2E * c)), -1.f);
        hnew = og * th;
    }

    if (isL1 && u < H_) {
        out[(size_t)b * H_ + u] = hnew;
    }
}

extern "C" void kernel_launch(void* const* d_in, const int* in_sizes, int n_in,
                              void* d_out, int out_size, void* d_ws, size_t ws_size,
                              hipStream_t stream) {
    const float* x    = (const float*)d_in[0];
    const float* Wih0 = (const float*)d_in[1];
    const float* Whh0 = (const float*)d_in[2];
    const float* bih0 = (const float*)d_in[3];
    const float* bhh0 = (const float*)d_in[4];
    const float* Wih1 = (const float*)d_in[5];
    const float* Whh1 = (const float*)d_in[6];
    const float* bih1 = (const float*)d_in[7];
    const float* bhh1 = (const float*)d_in[8];
    float* out = (float*)d_out;

    dim3 grid(B_ / BPB);
    dim3 block(256);
    lstm2_kernel<<<grid, block, 0, stream>>>(x, Wih0, Whh0, bih0, bhh0,
                                             Wih1, Whh1, bih1, bhh1, out);
}

// Round 4
// 537.519 us; speedup vs baseline: 1.3475x; 1.0600x over previous
//
#include <hip/hip_runtime.h>

// 2-layer LSTM: B=2048, T=512, F=60, H=7, PyTorch gate order (i,f,g,o).
//
// TWO-PHASE:
//  Phase 1 (proj_kernel): A[b][t][r] = bias0[r] + Wih0[r,:].x[b,t,:]  (fp32,
//    117 MB in d_ws). Fully parallel, memory-bound (~370 MB traffic).
//  Phase 2 (rec_kernel): wave = batch (2048 waves, 2/SIMD).
//    lanes 0..27  : layer0 gate rows, step t     (seed = A[b][t][r])
//    lanes 32..59 : layer1 gate rows, step t-1   (seed = bias1[r])
//    Per step: 1 prefetched 4B load + 2x dot7 + activation + 3 shfl gathers
//    + cell update + 14 readlane broadcasts. No LDS, no barriers, no spills.
//    a_in prefetched via an 8-deep register ring (state-independent loads).
// Falls back to the round-3 single kernel if ws_size < 117.4 MB.

#define B_ 2048
#define T_ 512
#define F_ 60
#define H_ 7
#define G4 28
#define BT_ (B_ * T_)
#define L2E 1.4426950408889634f
#define PD 8   // prefetch ring depth

#if __has_builtin(__builtin_amdgcn_exp2f)
#define EXP2(x) __builtin_amdgcn_exp2f(x)
#else
#define EXP2(x) exp2f(x)
#endif

__device__ __forceinline__ float rcpf_(float v) { return __builtin_amdgcn_rcpf(v); }

__device__ __forceinline__ float bcast(float v, int srclane) {
    return __uint_as_float(__builtin_amdgcn_readlane(__float_as_uint(v), srclane));
}

__device__ __forceinline__ float dot7(const float* w, const float* h, float seed) {
    float m01 = fmaf(w[1], h[1], w[0] * h[0]);
    float m23 = fmaf(w[3], h[3], w[2] * h[2]);
    float m45 = fmaf(w[5], h[5], w[4] * h[4]);
    float m6  = fmaf(w[6], h[6], seed);
    return (m01 + m23) + (m45 + m6);
}

// ---------------------------------------------------------------- phase 1
__global__ __launch_bounds__(256)
void proj_kernel(const float* __restrict__ x, const float* __restrict__ Wih0,
                 const float* __restrict__ bih0, const float* __restrict__ bhh0,
                 float* __restrict__ A)
{
    __shared__ float wsm[G4 * F_];   // 6720 B, broadcast reads (conflict-free)
    __shared__ float bsm[G4];

    for (int i = threadIdx.x; i < G4 * F_; i += 256) wsm[i] = Wih0[i];
    if (threadIdx.x < G4) bsm[threadIdx.x] = bih0[threadIdx.x] + bhh0[threadIdx.x];
    __syncthreads();

    const int bt = blockIdx.x * 256 + threadIdx.x;   // grid exactly covers BT_

    float xr[F_];
    const float4* __restrict__ xp = (const float4*)(x + (size_t)bt * F_);
    #pragma unroll
    for (int j = 0; j < 15; ++j) {
        float4 q = xp[j];
        xr[4 * j + 0] = q.x; xr[4 * j + 1] = q.y;
        xr[4 * j + 2] = q.z; xr[4 * j + 3] = q.w;
    }

    float4* __restrict__ Ap = (float4*)(A + (size_t)bt * G4);
    #pragma unroll
    for (int rg = 0; rg < 7; ++rg) {
        float s[4];
        #pragma unroll
        for (int q = 0; q < 4; ++q) {
            const int r = rg * 4 + q;
            const float* w = &wsm[r * F_];
            float a0 = bsm[r], a1 = 0.f, a2 = 0.f, a3 = 0.f;
            #pragma unroll
            for (int k = 0; k < F_; k += 4) {
                a0 = fmaf(w[k + 0], xr[k + 0], a0);
                a1 = fmaf(w[k + 1], xr[k + 1], a1);
                a2 = fmaf(w[k + 2], xr[k + 2], a2);
                a3 = fmaf(w[k + 3], xr[k + 3], a3);
            }
            s[q] = (a0 + a1) + (a2 + a3);
        }
        Ap[rg] = make_float4(s[0], s[1], s[2], s[3]);
    }
}

// ---------------------------------------------------------------- phase 2
__global__ __launch_bounds__(256)
void rec_kernel(const float* __restrict__ A,
                const float* __restrict__ Whh0,
                const float* __restrict__ Wih1, const float* __restrict__ Whh1,
                const float* __restrict__ bih1, const float* __restrict__ bhh1,
                float* __restrict__ out)
{
    const int tid   = threadIdx.x;
    const int lane  = tid & 63;
    const bool isL1 = lane >= 32;
    const int g     = lane & 31;
    const int r     = (g < G4) ? g : (G4 - 1);
    const int b     = blockIdx.x * 4 + (tid >> 6);

    float wA[H_], wB[H_];
    #pragma unroll
    for (int v = 0; v < H_; ++v) {
        wA[v] = isL1 ? Wih1[r * H_ + v] : Whh0[r * H_ + v];
        wB[v] = isL1 ? Whh1[r * H_ + v] : 0.f;
    }
    const float bias1 = bih1[r] + bhh1[r];

    const bool isT = (r >= 2 * H_ && r < 3 * H_);   // cell gate -> tanh
    const float KK = isT ? (-2.f * L2E) : (-L2E);
    const float Aa = isT ? 2.f : 1.f;
    const float Ca = isT ? -1.f : 0.f;

    float h0v[H_] = {0, 0, 0, 0, 0, 0, 0};
    float h1v[H_] = {0, 0, 0, 0, 0, 0, 0};
    float c = 0.f, hnew = 0.f;

    // lane's a_in column (clamped for idle lanes -> same cacheline, no extra BW)
    const float* __restrict__ pa = A + (size_t)b * T_ * G4 + r;

    float buf[PD];
    #pragma unroll
    for (int i = 0; i < PD; ++i) buf[i] = pa[i * G4];

    for (int tt = 0; tt < T_; tt += PD) {
        #pragma unroll
        for (int s = 0; s < PD; ++s) {
            const int t = tt + s;
            // issue next prefetch early (state-independent)
            const int tn = (t + PD < T_) ? (t + PD) : (T_ - 1);
            float nb = pa[(size_t)tn * G4];

            float seed = isL1 ? bias1 : buf[s];
            float a = dot7(wA, h0v, seed);
            a = dot7(wB, h1v, a);
            float act = fmaf(Aa, rcpf_(1.f + EXP2(KK * a)), Ca);

            float fg = __shfl(act, lane + 7, 64);
            float gg = __shfl(act, lane + 14, 64);
            float og = __shfl(act, lane + 21, 64);

            float cnew = fmaf(fg, c, act * gg);
            if (t == 0) cnew = isL1 ? 0.f : cnew;   // L1 phantom step
            c = cnew;
            float th = fmaf(2.f, rcpf_(1.f + EXP2(-2.f * L2E * c)), -1.f);
            hnew = og * th;
            // (t==0: L1 hnew = 0 -> broadcasts correct initial h1)

            #pragma unroll
            for (int v = 0; v < H_; ++v) h0v[v] = bcast(hnew, v);
            #pragma unroll
            for (int v = 0; v < H_; ++v) h1v[v] = bcast(hnew, 32 + v);

            buf[s] = nb;
        }
    }

    // epilogue: layer1 step T-1 (consumes h0(T-1), h1(T-2))
    {
        float a = dot7(wA, h0v, isL1 ? bias1 : 0.f);
        a = dot7(wB, h1v, a);
        float act = fmaf(Aa, rcpf_(1.f + EXP2(KK * a)), Ca);
        float fg = __shfl(act, lane + 7, 64);
        float gg = __shfl(act, lane + 14, 64);
        float og = __shfl(act, lane + 21, 64);
        c = fmaf(fg, c, act * gg);
        float th = fmaf(2.f, rcpf_(1.f + EXP2(-2.f * L2E * c)), -1.f);
        hnew = og * th;
    }

    if (isL1 && g < H_) out[(size_t)b * H_ + g] = hnew;
}

// ------------------------------------------- fallback (round-3 kernel, passing)
#define CH 16
#define NCH (T_ / CH)
#define F4 15
#define ROW4 (CH * F4)
#define BPB 4
#define TOT4 (BPB * ROW4)

__device__ __forceinline__ float proj32(const float* pw, const float4* rp, float seed) {
    float s0 = seed, s1 = 0.f, s2 = 0.f, s3 = 0.f;
    #pragma unroll
    for (int j = 0; j < 8; ++j) {
        float4 q = rp[j];
        s0 = fmaf(pw[4 * j + 0], q.x, s0);
        s1 = fmaf(pw[4 * j + 1], q.y, s1);
        s2 = fmaf(pw[4 * j + 2], q.z, s2);
        s3 = fmaf(pw[4 * j + 3], q.w, s3);
    }
    return (s0 + s1) + (s2 + s3);
}

__global__ __launch_bounds__(256, 2)
void lstm2_fallback(const float* __restrict__ x,
                    const float* __restrict__ Wih0, const float* __restrict__ Whh0,
                    const float* __restrict__ bih0, const float* __restrict__ bhh0,
                    const float* __restrict__ Wih1, const float* __restrict__ Whh1,
                    const float* __restrict__ bih1, const float* __restrict__ bhh1,
                    float* __restrict__ out)
{
    __shared__ float4 lds4[2][BPB][ROW4];

    const int tid   = threadIdx.x;
    const int lane  = tid & 63;
    const bool isL1 = lane >= 32;
    const int g     = lane & 31;
    const int r     = (g < G4) ? g : (G4 - 1);
    const int grp   = tid >> 6;
    const int b     = blockIdx.x * BPB + grp;

    float pw[32];
    {
        const int offs = isL1 ? 28 : 0;
        #pragma unroll
        for (int k = 0; k < 32; ++k) pw[k] = Wih0[r * F_ + offs + k];
        if (isL1) { pw[0] = pw[1] = pw[2] = pw[3] = 0.f; }
    }
    float wA[H_], wB[H_];
    #pragma unroll
    for (int v = 0; v < H_; ++v) {
        wA[v] = isL1 ? Wih1[r * H_ + v] : Whh0[r * H_ + v];
        wB[v] = isL1 ? Whh1[r * H_ + v] : 0.f;
    }
    const float bias0 = bih0[r] + bhh0[r];
    const float bias1 = bih1[r] + bhh1[r];

    const bool isT = (r >= 2 * H_ && r < 3 * H_);
    const float KK = isT ? (-2.f * L2E) : (-L2E);
    const float Aa = isT ? 2.f : 1.f;
    const float Ca = isT ? -1.f : 0.f;

    float h0v[H_] = {0, 0, 0, 0, 0, 0, 0};
    float h1v[H_] = {0, 0, 0, 0, 0, 0, 0};
    float c = 0.f, hnew = 0.f;

    const float4* __restrict__ xb =
        (const float4*)(x + (size_t)(blockIdx.x * BPB) * T_ * F_);
    const int XB4 = T_ * F4;
    const int lofs = isL1 ? 7 : 0;
    const float pseed = isL1 ? 0.f : bias0;

    #pragma unroll
    for (int i = 0; i < 4; ++i) {
        int idx = tid + 256 * i;
        if (idx < TOT4) {
            int bl = idx / ROW4;
            int j  = idx - bl * ROW4;
            lds4[0][bl][j] = xb[bl * XB4 + j];
        }
    }
    __syncthreads();

    float a_in;
    {
        float ow = proj32(pw, &lds4[0][grp][0] + lofs, pseed);
        a_in = ow + __shfl(ow, lane ^ 32, 64);
    }

    for (int ch = 0; ch < NCH; ++ch) {
        const int cn = (ch < NCH - 1) ? ch + 1 : ch;
        float4 st[4];
        #pragma unroll
        for (int i = 0; i < 4; ++i) {
            int idx = tid + 256 * i;
            if (idx < TOT4) {
                int bl = idx / ROW4;
                int j  = idx - bl * ROW4;
                st[i] = xb[bl * XB4 + cn * ROW4 + j];
            }
        }

        const int buf = ch & 1;
        const float4* __restrict__ rowb = &lds4[buf][grp][0] + lofs;

        #pragma unroll
        for (int s = 0; s < CH; ++s) {
            float seed = isL1 ? bias1 : a_in;
            float a = dot7(wA, h0v, seed);
            a = dot7(wB, h1v, a);
            float act = fmaf(Aa, rcpf_(1.f + EXP2(KK * a)), Ca);

            float fg = __shfl(act, lane + 7, 64);
            float gg = __shfl(act, lane + 14, 64);
            float og = __shfl(act, lane + 21, 64);

            float cnew = fmaf(fg, c, act * gg);
            if (ch == 0 && s == 0) cnew = isL1 ? 0.f : cnew;
            c = cnew;
            float th = fmaf(2.f, rcpf_(1.f + EXP2(-2.f * L2E * c)), -1.f);
            hnew = og * th;

            #pragma unroll
            for (int v = 0; v < H_; ++v) h0v[v] = bcast(hnew, v);
            if (ch > 0 || s > 0) {
                #pragma unroll
                for (int v = 0; v < H_; ++v) h1v[v] = bcast(hnew, 32 + v);
            }

            if (s < CH - 1) {
                float ow = proj32(pw, rowb + (s + 1) * F4, pseed);
                a_in = ow + __shfl(ow, lane ^ 32, 64);
            }
        }

        #pragma unroll
        for (int i = 0; i < 4; ++i) {
            int idx = tid + 256 * i;
            if (idx < TOT4) {
                int bl = idx / ROW4;
                int j  = idx - bl * ROW4;
                lds4[buf ^ 1][bl][j] = st[i];
            }
        }
        __syncthreads();

        if (ch < NCH - 1) {
            float ow = proj32(pw, &lds4[buf ^ 1][grp][0] + lofs, pseed);
            a_in = ow + __shfl(ow, lane ^ 32, 64);
        }
    }

    {
        float a = dot7(wA, h0v, isL1 ? bias1 : 0.f);
        a = dot7(wB, h1v, a);
        float act = fmaf(Aa, rcpf_(1.f + EXP2(KK * a)), Ca);
        float fg = __shfl(act, lane + 7, 64);
        float gg = __shfl(act, lane + 14, 64);
        float og = __shfl(act, lane + 21, 64);
        c = fmaf(fg, c, act * gg);
        float th = fmaf(2.f, rcpf_(1.f + EXP2(-2.f * L2E * c)), -1.f);
        hnew = og * th;
    }

    if (isL1 && g < H_) out[(size_t)b * H_ + g] = hnew;
}

extern "C" void kernel_launch(void* const* d_in, const int* in_sizes, int n_in,
                              void* d_out, int out_size, void* d_ws, size_t ws_size,
                              hipStream_t stream) {
    const float* x    = (const float*)d_in[0];
    const float* Wih0 = (const float*)d_in[1];
    const float* Whh0 = (const float*)d_in[2];
    const float* bih0 = (const float*)d_in[3];
    const float* bhh0 = (const float*)d_in[4];
    const float* Wih1 = (const float*)d_in[5];
    const float* Whh1 = (const float*)d_in[6];
    const float* bih1 = (const float*)d_in[7];
    const float* bhh1 = (const float*)d_in[8];
    float* out = (float*)d_out;

    const size_t need = (size_t)BT_ * G4 * sizeof(float);   // 117,440,512 B
    if (ws_size >= need) {
        float* A = (float*)d_ws;
        proj_kernel<<<dim3(BT_ / 256), dim3(256), 0, stream>>>(x, Wih0, bih0, bhh0, A);
        rec_kernel<<<dim3(B_ / 4), dim3(256), 0, stream>>>(A, Whh0, Wih1, Whh1,
                                                           bih1, bhh1, out);
    } else {
        lstm2_fallback<<<dim3(B_ / BPB), dim3(256), 0, stream>>>(
            x, Wih0, Whh0, bih0, bhh0, Wih1, Whh1, bih1, bhh1, out);
    }
}